// Round 1
// baseline (4999.035 us; speedup 1.0000x reference)
//
#include <hip/hip_runtime.h>
#include <cmath>

#define B_ 64
#define T_ 512
#define I_ 1024
#define H_ 1024

// ---------------------------------------------------------------------------
// Kernel 1: xw[m, n] = sum_k x[m,k] * W[n,k] + bW[n]   (M=32768, N=1024, K=1024)
// Written into the out1 region of d_out. 128x128 tile, BK=8, 8x8 per thread.
// (unchanged from verified baseline)
// ---------------------------------------------------------------------------
#define TS 128
#define KS 8

__global__ __launch_bounds__(256) void gemm_xw(const float* __restrict__ x,
                                               const float* __restrict__ W,
                                               const float* __restrict__ bW,
                                               float* __restrict__ out) {
    __shared__ float As[KS][TS];
    __shared__ float Bs[KS][TS];

    const int tid = threadIdx.x;
    const int tx = tid & 15;
    const int ty = tid >> 4;
    const int m0 = blockIdx.y * TS;
    const int n0 = blockIdx.x * TS;

    const int lr = tid >> 1;
    const int lk = (tid & 1) * 4;

    const float* xa = x + (size_t)(m0 + lr) * I_ + lk;
    const float* wb = W + (size_t)(n0 + lr) * I_ + lk;

    float acc[8][8] = {};

    for (int k0 = 0; k0 < I_; k0 += KS) {
        float4 a = *(const float4*)(xa + k0);
        float4 bv = *(const float4*)(wb + k0);
        __syncthreads();
        As[lk + 0][lr] = a.x;  As[lk + 1][lr] = a.y;
        As[lk + 2][lr] = a.z;  As[lk + 3][lr] = a.w;
        Bs[lk + 0][lr] = bv.x; Bs[lk + 1][lr] = bv.y;
        Bs[lk + 2][lr] = bv.z; Bs[lk + 3][lr] = bv.w;
        __syncthreads();
#pragma unroll
        for (int kk = 0; kk < KS; ++kk) {
            float av[8], bw8[8];
            *(float4*)&av[0]  = *(const float4*)&As[kk][ty * 8];
            *(float4*)&av[4]  = *(const float4*)&As[kk][ty * 8 + 4];
            *(float4*)&bw8[0] = *(const float4*)&Bs[kk][tx * 8];
            *(float4*)&bw8[4] = *(const float4*)&Bs[kk][tx * 8 + 4];
#pragma unroll
            for (int i = 0; i < 8; ++i)
#pragma unroll
                for (int j = 0; j < 8; ++j)
                    acc[i][j] += av[i] * bw8[j];
        }
    }

    float bias[8];
    *(float4*)&bias[0] = *(const float4*)&bW[n0 + tx * 8];
    *(float4*)&bias[4] = *(const float4*)&bW[n0 + tx * 8 + 4];
#pragma unroll
    for (int i = 0; i < 8; ++i) {
        float* o = out + (size_t)(m0 + ty * 8 + i) * H_ + n0 + tx * 8;
        float4 v0, v1;
        v0.x = acc[i][0] + bias[0]; v0.y = acc[i][1] + bias[1];
        v0.z = acc[i][2] + bias[2]; v0.w = acc[i][3] + bias[3];
        v1.x = acc[i][4] + bias[4]; v1.y = acc[i][5] + bias[5];
        v1.z = acc[i][6] + bias[6]; v1.w = acc[i][7] + bias[7];
        *(float4*)(o)     = v0;
        *(float4*)(o + 4) = v1;
    }
}

// ---------------------------------------------------------------------------
// Kernel 2: persistent recurrence, batch-grouped partition.
// 256 WGs x 256 threads. WG g: p = g&7 (batches 8p..8p+8),
// q = g>>3 (cols 32q..32q+32). U slice (32 rows, 128K+pad) resident in LDS.
//
// Per step: each WG's h3 slice (8 batches x 1024) is produced entirely by
// the 32 WGs of its own batch group -> group-local all-gather barrier
// (32 flags, no central go-broadcast). h3 exchanged via double-buffered hx
// in d_ws with agent-scope relaxed atomics (L3-coherent).
//
// GEMV: thread (tile=tid>>4, kq=tid&15): tile = 2 batch-subtiles x 8
// col-subtiles of 4x4 outputs; k = m*32 + 2kq + {0,1}, m=0..31, 4-deep
// ull prefetch from hx. 16-way k-reduction via 4 shfl_xor butterflies;
// owner-select lands result on the tanh-owner thread.
// ---------------------------------------------------------------------------
#define UROW 1088   // 32 chunks * 34 floats (32 data + 2 pad)

typedef unsigned long long ull;

__device__ __forceinline__ ull aload(const ull* p) {
    return __hip_atomic_load(p, __ATOMIC_RELAXED, __HIP_MEMORY_SCOPE_AGENT);
}
__device__ __forceinline__ unsigned aload32(const unsigned* p) {
    return __hip_atomic_load(p, __ATOMIC_RELAXED, __HIP_MEMORY_SCOPE_AGENT);
}

__global__ __launch_bounds__(256) void rnn_scan(const float* __restrict__ U,
                                                const float* __restrict__ bU,
                                                float* __restrict__ out,
                                                float* __restrict__ hx0,
                                                float* __restrict__ hx1,
                                                unsigned* __restrict__ flags) {
    __shared__ float Ul[32][UROW];   // 139264 B

    const int g = blockIdx.x;
    const int p = g & 7;          // batch group
    const int q = g >> 3;         // col group
    const int tid = threadIdx.x;

    const int tile = tid >> 4;    // 0..15
    const int kq = tid & 15;      // 0..15
    const int bt = tile >> 3;     // 0..1
    const int ct4 = (tile & 7) * 4;

    // owner identity: bijective over tid
    const int b = p * 8 + bt * 4 + (kq >> 2);
    const int h = q * 32 + ct4 + (kq & 3);

    // --- stage U rows [32q, 32q+32) into LDS, chunk-interleaved layout ---
    {
        const int m = tid >> 3;          // (tid*4)>>5
        const int w = (tid & 7) * 4;     // (tid*4)&31
        float* dst = &Ul[0][m * 34 + w];
        const float* src = U + (size_t)q * 32 * H_ + tid * 4;
#pragma unroll 4
        for (int r = 0; r < 32; ++r)
            *(float4*)(dst + (size_t)r * UROW) = *(const float4*)(src + (size_t)r * H_);
    }
    __syncthreads();

    const float bUh = bU[h];
    float s = 0.0f;
    float* out2 = out + (size_t)B_ * T_ * H_;

    const int r0 = p * 8 + bt * 4;   // GEMV batch base (4 rows)

    float xwv = out[(size_t)b * T_ * H_ + h];   // xw for t=0

    for (int t = 0; t < T_; ++t) {
        // (a) elementwise: h3 = tanh(xw + s); out1 in place
        const size_t rowoff = ((size_t)b * T_ + t) * H_;
        float h3 = tanhf(xwv + s);
        out[rowoff + h] = h3;
        if (t == T_ - 1) {
            out2[(size_t)b * H_ + h] = h3;
            break;
        }

        float* hx = (t & 1) ? hx1 : hx0;
        __hip_atomic_store((unsigned*)hx + (size_t)b * H_ + h, __float_as_uint(h3),
                           __ATOMIC_RELAXED, __HIP_MEMORY_SCOPE_AGENT);

        // (b) group barrier: syncthreads drains vmcnt (h3 stores at L3),
        // then raise own flag; all-gather the 32 group flags.
        __syncthreads();
        const unsigned gen = (unsigned)(t + 1);
        if (tid == 0)
            __hip_atomic_store(&flags[g], gen, __ATOMIC_RELAXED,
                               __HIP_MEMORY_SCOPE_AGENT);

        // prefetch next step's xw while waiting (row owned by this thread)
        xwv = out[rowoff + H_ + h];

        if (tid < 32) {
            const unsigned* f = &flags[p + 8 * tid];
            // '<' not '!=': a fast group member may advance its flag past
            // gen before we poll. flags memset to 0 on stream each launch.
            while (aload32(f) < gen) {}
        }
        __syncthreads();

        // (c) GEMV partials: batches r0..r0+3, local cols ct4..ct4+3,
        // k = m*32 + 2kq + {0,1}
        const ull* hx8 = (const ull*)hx;
        ull pf[4][4];
#pragma unroll
        for (int d = 0; d < 4; ++d)
#pragma unroll
            for (int i = 0; i < 4; ++i)
                pf[d][i] = aload(hx8 + (size_t)(r0 + i) * 512 + d * 16 + kq);

        float acc[4][4] = {};
#pragma unroll
        for (int m = 0; m < 32; ++m) {
            const int slot = m & 3;
            float2 hh[4];
#pragma unroll
            for (int i = 0; i < 4; ++i) {
                ull v = pf[slot][i];
                hh[i].x = __uint_as_float((unsigned)(v & 0xffffffffu));
                hh[i].y = __uint_as_float((unsigned)(v >> 32));
            }
            if (m < 28) {
#pragma unroll
                for (int i = 0; i < 4; ++i)
                    pf[slot][i] =
                        aload(hx8 + (size_t)(r0 + i) * 512 + (m + 4) * 16 + kq);
            }
#pragma unroll
            for (int c = 0; c < 4; ++c) {
                float2 uu = *(const float2*)&Ul[ct4 + c][m * 34 + kq * 2];
#pragma unroll
                for (int i = 0; i < 4; ++i)
                    acc[i][c] += hh[i].x * uu.x + hh[i].y * uu.y;
            }
        }

        // 16-way k-reduction over the kq lane bits
#pragma unroll
        for (int i = 0; i < 4; ++i)
#pragma unroll
            for (int c = 0; c < 4; ++c) {
                float v = acc[i][c];
                v += __shfl_xor(v, 1);
                v += __shfl_xor(v, 2);
                v += __shfl_xor(v, 4);
                v += __shfl_xor(v, 8);
                acc[i][c] = v;
            }

        // select this thread's (b,h): i = kq>>2, c = kq&3
        float r = acc[0][0];
#pragma unroll
        for (int i = 0; i < 4; ++i)
#pragma unroll
            for (int c = 0; c < 4; ++c)
                if (((kq >> 2) == i) && ((kq & 3) == c)) r = acc[i][c];

        s = bUh + r;
    }
}

// ---------------------------------------------------------------------------
extern "C" void kernel_launch(void* const* d_in, const int* in_sizes, int n_in,
                              void* d_out, int out_size, void* d_ws, size_t ws_size,
                              hipStream_t stream) {
    const float* x  = (const float*)d_in[0];
    const float* W  = (const float*)d_in[1];
    const float* bW = (const float*)d_in[2];
    const float* U  = (const float*)d_in[3];
    const float* bU = (const float*)d_in[4];
    float* out = (float*)d_out;

    float* hx0 = (float*)d_ws;
    float* hx1 = hx0 + (size_t)B_ * H_;
    unsigned* flags = (unsigned*)(hx1 + (size_t)B_ * H_);

    // flags must start below gen=1 for the '<' spin; don't trust ws contents
    hipMemsetAsync(flags, 0, 256 * sizeof(unsigned), stream);

    dim3 g1(H_ / TS, (B_ * T_) / TS);
    gemm_xw<<<g1, dim3(256), 0, stream>>>(x, W, bW, out);

    void* args[] = {(void*)&U, (void*)&bU, (void*)&out,
                    (void*)&hx0, (void*)&hx1, (void*)&flags};
    hipLaunchCooperativeKernel((void*)rnn_scan, dim3(256), dim3(256), args, 0,
                               stream);
}